// Round 10
// baseline (132.669 us; speedup 1.0000x reference)
//
#include <hip/hip_runtime.h>

// ---------------- workspace layout (float offsets) ----------------
// Bit split of the 64-step sequence: V=14 | 8,7,7,7,7 | W=14
// V  : 2^14 x 16 vectors (bits t=0..13, includes left fold)         1 MB
// W  : 2^14 x 16 vectors (bits t=50..63, includes right fold)       1 MB
// P  : chunk tables, row-major 16x16 each:
//      c0: 2^8 mats (t=14..21), c1..c4: 2^7 mats (t=22.. / 29.. / 36.. / 43..)
//      768 matrices total                                          0.75 MB
// Total hot table = 2.75 MB -> fits per-XCD 4MB L2 with slack.
#define OFF_V    0u
#define OFF_W    262144u
#define OFF_P    524288u
#define OFF_VA   720896u
#define OFF_WB   722944u
#define OFF_PAV  724992u
#define OFF_PAW  757760u
// total 790528 floats = 3.0 MB of d_ws
// chunk bases inside P (floats): c0=0, c1=65536, c2=98304, c3=131072, c4=163840

__device__ __forceinline__ void rmul16(float* v, const float* B) {
  float nv[16];
#pragma unroll
  for (int e = 0; e < 16; ++e) {
    float a = 0.f;
#pragma unroll
    for (int d = 0; d < 16; ++d) a = fmaf(v[d], B[d * 16 + e], a);
    nv[e] = a;
  }
#pragma unroll
  for (int e = 0; e < 16; ++e) v[e] = nv[e];
}

__device__ __forceinline__ void lmul16(float* v, const float* B) {
  float nv[16];
#pragma unroll
  for (int d = 0; d < 16; ++d) {
    float a = 0.f;
#pragma unroll
    for (int e = 0; e < 16; ++e) a = fmaf(B[d * 16 + e], v[e], a);
    nv[d] = a;
  }
#pragma unroll
  for (int d = 0; d < 16; ++d) v[d] = nv[d];
}

// ---------------- phase A: piece chains + direct chunk builds (65 blocks) ----
// gid 0..127: VA (7-bit vector chains, t=0..6, left fold)
// gid 128..255: WB (7-bit vector chains, t=57..63, right fold)
// gid 256..2303: PAV column chains (t=7..13)
// gid 2304..4351: PAW column chains (t=50..56)
// gid 4352..16639: direct chunk-matrix column chains (768 mats x 16 cols)
__global__ __launch_bounds__(256) void build_a(const float* __restrict__ left,
                                               const float* __restrict__ bulk,
                                               const float* __restrict__ right,
                                               float* __restrict__ ws) {
  __shared__ float Bs[2][256];
  __shared__ float Ls[2][16];
  __shared__ float Rs[2][16];
  int tid = threadIdx.x;
  for (int i = tid; i < 576; i += 256) {
    if (i < 512) Bs[i & 1][i >> 1] = bulk[i];
    else if (i < 544) { int j = i - 512; Ls[j & 1][j >> 1] = left[j]; }
    else              { int j = i - 544; Rs[j & 1][j >> 1] = right[j]; }
  }
  __syncthreads();

  unsigned gid = blockIdx.x * 256 + tid;
  float v[16];
  if (gid < 128) {
    unsigned i = gid;
#pragma unroll
    for (int d = 0; d < 16; ++d) v[d] = Ls[i & 1][d];
    for (int t = 1; t <= 6; ++t) rmul16(v, Bs[(i >> t) & 1]);
#pragma unroll
    for (int d = 0; d < 16; ++d) ws[OFF_VA + i * 16 + d] = v[d];
  } else if (gid < 256) {
    unsigned i = gid - 128;
#pragma unroll
    for (int d = 0; d < 16; ++d) v[d] = Rs[(i >> 6) & 1][d];
    for (int p = 5; p >= 0; --p) lmul16(v, Bs[(i >> p) & 1]);
#pragma unroll
    for (int d = 0; d < 16; ++d) ws[OFF_WB + i * 16 + d] = v[d];
  } else if (gid < 2304) {
    unsigned it = gid - 256, i = it >> 4, col = it & 15;
#pragma unroll
    for (int d = 0; d < 16; ++d) v[d] = Bs[(i >> 6) & 1][d * 16 + col];
    for (int p = 5; p >= 0; --p) lmul16(v, Bs[(i >> p) & 1]);
#pragma unroll
    for (int d = 0; d < 16; ++d) ws[OFF_PAV + i * 256 + d * 16 + col] = v[d];
  } else if (gid < 4352) {
    unsigned it = gid - 2304, i = it >> 4, col = it & 15;
#pragma unroll
    for (int d = 0; d < 16; ++d) v[d] = Bs[(i >> 6) & 1][d * 16 + col];
    for (int p = 5; p >= 0; --p) lmul16(v, Bs[(i >> p) & 1]);
#pragma unroll
    for (int d = 0; d < 16; ++d) ws[OFF_PAW + i * 256 + d * 16 + col] = v[d];
  } else {
    // direct chunk builds: matrix id mi in 0..767, column col.
    // chunk product = M(bit0)*M(bit1)*...*M(bit_{w-1}), bit j <-> t0+j;
    // column chain built right-to-left: start col of M(bit_{w-1}), lmul down.
    unsigned it = gid - 4352, mi = it >> 4, col = it & 15;
    if (mi < 256) {
      unsigned i = mi;  // chunk 0, w=8
#pragma unroll
      for (int d = 0; d < 16; ++d) v[d] = Bs[(i >> 7) & 1][d * 16 + col];
      for (int p = 6; p >= 0; --p) lmul16(v, Bs[(i >> p) & 1]);
#pragma unroll
      for (int d = 0; d < 16; ++d) ws[OFF_P + i * 256 + d * 16 + col] = v[d];
    } else {
      unsigned r = mi - 256;
      unsigned c = r >> 7, i = r & 127;  // chunks 1..4, w=7
      unsigned base = 65536u + c * 32768u;
#pragma unroll
      for (int d = 0; d < 16; ++d) v[d] = Bs[(i >> 6) & 1][d * 16 + col];
      for (int p = 5; p >= 0; --p) lmul16(v, Bs[(i >> p) & 1]);
#pragma unroll
      for (int d = 0; d < 16; ++d) ws[OFF_P + base + i * 256 + d * 16 + col] = v[d];
    }
  }
}

// ---------------- phase B: V/W combines only (2048 blocks) ----------------
__global__ __launch_bounds__(256) void build_b(float* __restrict__ ws) {
  unsigned gid = blockIdx.x * 256 + threadIdx.x;
  if (gid < 262144u) {
    // V[i][e] = sum_k VA[i&127][k] * PAV[i>>7][k][e]
    unsigned i = gid >> 4, e = gid & 15;
    const float* va = ws + OFF_VA + (i & 127) * 16;
    const float* pm = ws + OFF_PAV + (i >> 7) * 256;
    float a = 0.f;
#pragma unroll
    for (int k = 0; k < 16; ++k) a = fmaf(va[k], pm[k * 16 + e], a);
    ws[OFF_V + (size_t)i * 16 + e] = a;
  } else {
    // W[i][d] = sum_k PAW[i&127][d][k] * WB[i>>7][k]
    unsigned g = gid - 262144u, i = g >> 4, d = g & 15;
    const float* wb = ws + OFF_WB + (i >> 7) * 16;
    const float* pm = ws + OFF_PAW + (i & 127) * 256 + d * 16;
    float a = 0.f;
#pragma unroll
    for (int k = 0; k < 16; ++k) a = fmaf(pm[k], wb[k], a);
    ws[OFF_W + (size_t)i * 16 + d] = a;
  }
}

// ---------------- main kernel: 16 lanes per sequence, 5 chunks ----------------
// block 256 = 4 waves; each wave handles 4 sequences (lane e = output elem).
// All chunk operand columns (80 scalars/lane) loaded upfront for MLP;
// per-chunk m-broadcast via wave-synchronous LDS roundtrip (no barrier).
// x loads are nontemporal so the 33.5MB stream doesn't evict the 2.75MB table.
__global__ __launch_bounds__(256, 4) void mps_main(const int* __restrict__ x,
                                                   const float* __restrict__ ws,
                                                   float* __restrict__ out) {
  __shared__ float sm[4][4][16];
  const int tid = threadIdx.x;
  const int lane = tid & 63;
  const int wave = tid >> 6;
  const int grp = lane >> 4;
  const int e = lane & 15;
  const unsigned seqw = blockIdx.x * 16u + wave * 4u;  // first seq of this wave
  const int* __restrict__ xp = x + (size_t)seqw * 64;

  // coalesced ballot-transpose: lane = column t, one row per ballot
  int v0 = __builtin_nontemporal_load(xp + lane);
  int v1 = __builtin_nontemporal_load(xp + 64 + lane);
  int v2 = __builtin_nontemporal_load(xp + 128 + lane);
  int v3 = __builtin_nontemporal_load(xp + 192 + lane);
  unsigned long long b0 = __ballot(v0 & 1);
  unsigned long long b1 = __ballot(v1 & 1);
  unsigned long long b2 = __ballot(v2 & 1);
  unsigned long long b3 = __ballot(v3 & 1);
  unsigned long long bits = (grp & 2) ? ((grp & 1) ? b3 : b2)
                                      : ((grp & 1) ? b1 : b0);

  const unsigned i0 = (unsigned)(bits & 0x3FFFull);
  const unsigned iw = (unsigned)(bits >> 50);
  unsigned idx0 = (unsigned)((bits >> 14) & 255ull);
  unsigned idx1 = (unsigned)((bits >> 22) & 127ull);
  unsigned idx2 = (unsigned)((bits >> 29) & 127ull);
  unsigned idx3 = (unsigned)((bits >> 36) & 127ull);
  unsigned idx4 = (unsigned)((bits >> 43) & 127ull);

  // issue ALL gathers upfront (V, W, 5x16 chunk columns) — max MLP,
  // each instruction is a 64B-coalesced line per 16-lane group
  float mv = ws[OFF_V + (size_t)i0 * 16 + e];
  float w  = ws[OFF_W + (size_t)iw * 16 + e];

  const float* __restrict__ P0 = ws + OFF_P;
  float p[5][16];
  {
    const float* pb = P0 + (size_t)idx0 * 256 + e;
#pragma unroll
    for (int d = 0; d < 16; ++d) p[0][d] = pb[d * 16];
  }
  {
    const float* pb = P0 + 65536u + (size_t)idx1 * 256 + e;
#pragma unroll
    for (int d = 0; d < 16; ++d) p[1][d] = pb[d * 16];
  }
  {
    const float* pb = P0 + 98304u + (size_t)idx2 * 256 + e;
#pragma unroll
    for (int d = 0; d < 16; ++d) p[2][d] = pb[d * 16];
  }
  {
    const float* pb = P0 + 131072u + (size_t)idx3 * 256 + e;
#pragma unroll
    for (int d = 0; d < 16; ++d) p[3][d] = pb[d * 16];
  }
  {
    const float* pb = P0 + 163840u + (size_t)idx4 * 256 + e;
#pragma unroll
    for (int d = 0; d < 16; ++d) p[4][d] = pb[d * 16];
  }

#pragma unroll
  for (int ch = 0; ch < 5; ++ch) {
    // wave-synchronous broadcast of m within each 16-lane group:
    // DS ops from one wave complete in order; asm barriers stop reordering.
    sm[wave][grp][e] = mv;
    asm volatile("" ::: "memory");
    float4 M0 = *(const float4*)&sm[wave][grp][0];
    float4 M1 = *(const float4*)&sm[wave][grp][4];
    float4 M2 = *(const float4*)&sm[wave][grp][8];
    float4 M3 = *(const float4*)&sm[wave][grp][12];
    asm volatile("" ::: "memory");
    float a0 = M0.x * p[ch][0];
    float a1 = M0.y * p[ch][1];
    float a2 = M0.z * p[ch][2];
    float a3 = M0.w * p[ch][3];
    a0 = fmaf(M1.x, p[ch][4], a0);
    a1 = fmaf(M1.y, p[ch][5], a1);
    a2 = fmaf(M1.z, p[ch][6], a2);
    a3 = fmaf(M1.w, p[ch][7], a3);
    a0 = fmaf(M2.x, p[ch][8], a0);
    a1 = fmaf(M2.y, p[ch][9], a1);
    a2 = fmaf(M2.z, p[ch][10], a2);
    a3 = fmaf(M2.w, p[ch][11], a3);
    a0 = fmaf(M3.x, p[ch][12], a0);
    a1 = fmaf(M3.y, p[ch][13], a1);
    a2 = fmaf(M3.z, p[ch][14], a2);
    a3 = fmaf(M3.w, p[ch][15], a3);
    mv = (a0 + a1) + (a2 + a3);
  }

  // final dot with W vector, reduce across the 16-lane group
  float part = mv * w;
  part += __shfl_xor(part, 1, 64);
  part += __shfl_xor(part, 2, 64);
  part += __shfl_xor(part, 4, 64);
  part += __shfl_xor(part, 8, 64);
  if (e == 0) out[seqw + grp] = part;
}

extern "C" void kernel_launch(void* const* d_in, const int* in_sizes, int n_in,
                              void* d_out, int out_size, void* d_ws, size_t ws_size,
                              hipStream_t stream) {
  const int* x = (const int*)d_in[0];
  const float* left = (const float*)d_in[1];
  const float* bulk = (const float*)d_in[2];
  const float* right = (const float*)d_in[3];
  float* out = (float*)d_out;
  float* ws = (float*)d_ws;

  int nseq = in_sizes[0] / 64;  // 131072

  build_a<<<65, 256, 0, stream>>>(left, bulk, right, ws);
  build_b<<<2048, 256, 0, stream>>>(ws);
  mps_main<<<nseq / 16, 256, 0, stream>>>(x, ws, out);
}